// Round 5
// baseline (121.070 us; speedup 1.0000x reference)
//
#include <hip/hip_runtime.h>
#include <hip/hip_bf16.h>

typedef short bf16x8 __attribute__((ext_vector_type(8)));
typedef short bf16x4 __attribute__((ext_vector_type(4)));
typedef float f32x4  __attribute__((ext_vector_type(4)));

#define NI 256
#define NJ 256
#define NC 128
#define NH 4
#define ND 32

// ---- workspace layout (bytes) ----
#define WB_OFF    0           // wqkv bf16 [384][128]  (row = op*128 + h*32 + d)
#define WO_BF_OFF 98304       // wo bf16 [128][128]
#define XN_OFF    131072      // xn bf16 [65536 tok][128]
#define TBM_OFF   16908288    // [1024 ih][256] f32 (tb + mask bias)
#define OG_OFF    17956864    // O bf16 [4 h][65536 tok][32]

__device__ __forceinline__ short f2bf(float f) {
    return __builtin_bit_cast(short, __float2bfloat16(f));
}

// Exchange: input pe[r] = val(idx = g*4+r), po[r] = val(idx = 16+g*4+r)  (idx in [0,32))
// output bf16x8: j -> val(idx = g*8+j)   == MFMA A/B-fragment k-slot layout.
// src lane for (g, j): group (g&1)*2 + (j>>2), same l16; register parity = g>>1; r = j&3.
__device__ __forceinline__ bf16x8 xchg(f32x4 pe, f32x4 po, int gg, int ll) {
    union P { int d; short s[2]; };
    P e0, e1, o0, o1;
    e0.s[0] = f2bf(pe[0]); e0.s[1] = f2bf(pe[1]);
    e1.s[0] = f2bf(pe[2]); e1.s[1] = f2bf(pe[3]);
    o0.s[0] = f2bf(po[0]); o0.s[1] = f2bf(po[1]);
    o1.s[0] = f2bf(po[2]); o1.s[1] = f2bf(po[3]);
    const int sA = ((gg & 1) * 2) * 16 + ll;       // for j=0..3
    const int sB = sA + 16;                        // for j=4..7
    const bool hi = gg >= 2;
    int t0e = __shfl(e0.d, sA), t0o = __shfl(o0.d, sA);
    int t1e = __shfl(e1.d, sA), t1o = __shfl(o1.d, sA);
    int t2e = __shfl(e0.d, sB), t2o = __shfl(o0.d, sB);
    int t3e = __shfl(e1.d, sB), t3o = __shfl(o1.d, sB);
    union U { int d[4]; bf16x8 v; } u;
    u.d[0] = hi ? t0o : t0e;
    u.d[1] = hi ? t1o : t1e;
    u.d[2] = hi ? t2o : t2e;
    u.d[3] = hi ? t3o : t3e;
    return u.v;
}

// ================= k_pre: LN + tb + mask bias (blocks 0..1023) ; weight conv (1024..1055) =================
__global__ __launch_bounds__(256, 8)
void k_pre(const float* __restrict__ x, const float* __restrict__ mask,
           const float* __restrict__ ln_g, const float* __restrict__ ln_b,
           const float* __restrict__ wb, const float* __restrict__ wq,
           const float* __restrict__ wk, const float* __restrict__ wv,
           const float* __restrict__ wo, char* __restrict__ ws)
{
    const int bid = blockIdx.x;
    const int tid = threadIdx.x;

    if (bid >= 1024) {   // ---- weight f32 -> bf16 ----
        const int base = ((bid - 1024) * 256 + tid) * 8;   // 65536 elems total
        const float* src;
        short* dst;
        if (base < 49152) {
            const int t = base >> 14;   // 0=q 1=k 2=v
            src = (t == 0 ? wq : (t == 1 ? wk : wv)) + (base & 16383);
            dst = (short*)(ws + WB_OFF) + base;
        } else {
            src = wo + (base - 49152);
            dst = (short*)(ws + WO_BF_OFF) + (base - 49152);
        }
        #pragma unroll
        for (int u = 0; u < 2; ++u) {
            f32x4 v = *(const f32x4*)(src + 4 * u);
            bf16x4 o;
            #pragma unroll
            for (int r = 0; r < 4; ++r) o[r] = f2bf(v[r]);
            *(bf16x4*)(dst + 4 * u) = o;
        }
        return;
    }

    // ---- LayerNorm: 4 threads per token, 64 tokens per block ----
    const int t   = tid >> 2;
    const int p   = tid & 3;
    const int ch  = p * 32;
    const size_t tok = (size_t)bid * 64 + t;

    const float* xr = x + tok * NC + ch;
    f32x4 vx[8];
    float s0 = 0.f;
    #pragma unroll
    for (int u = 0; u < 8; ++u) {
        vx[u] = *(const f32x4*)(xr + 4 * u);
        s0 += vx[u][0] + vx[u][1] + vx[u][2] + vx[u][3];
    }
    s0 += __shfl_xor(s0, 1);
    s0 += __shfl_xor(s0, 2);
    const float mu = s0 * 0.0078125f;
    float v0 = 0.f;
    #pragma unroll
    for (int u = 0; u < 8; ++u) {
        #pragma unroll
        for (int e = 0; e < 4; ++e) { float d = vx[u][e] - mu; v0 += d * d; }
    }
    v0 += __shfl_xor(v0, 1);
    v0 += __shfl_xor(v0, 2);
    const float rs = rsqrtf(v0 * 0.0078125f + 1e-5f);
    #pragma unroll
    for (int u = 0; u < 8; ++u) {
        f32x4 gg = *(const f32x4*)(ln_g + ch + 4 * u);
        f32x4 bb = *(const f32x4*)(ln_b + ch + 4 * u);
        #pragma unroll
        for (int e = 0; e < 4; ++e) vx[u][e] = (vx[u][e] - mu) * rs * gg[e] + bb[e];
    }

    // tb per head (f32), reduced over the 4 token-threads
    float tb[4];
    #pragma unroll
    for (int h = 0; h < 4; ++h) {
        const float* wr = wb + h * NC + ch;
        float a = 0.f;
        #pragma unroll
        for (int u = 0; u < 8; ++u) {
            f32x4 w4 = *(const f32x4*)(wr + 4 * u);
            #pragma unroll
            for (int e = 0; e < 4; ++e) a += vx[u][e] * w4[e];
        }
        a += __shfl_xor(a, 1);
        a += __shfl_xor(a, 2);
        tb[h] = a;
    }
    if (p == 0) {
        const float mb = 1.0e9f * (mask[tok] - 1.0f);
        const size_t i = tok >> 8, j = tok & 255;
        float* tbm = (float*)(ws + TBM_OFF);
        #pragma unroll
        for (int h = 0; h < 4; ++h)
            tbm[(i * NH + h) * NJ + j] = tb[h] + mb;
    }

    short* xnrow = (short*)(ws + XN_OFF) + tok * NC + ch;
    #pragma unroll
    for (int cc = 0; cc < 4; ++cc) {
        bf16x8 o8;
        #pragma unroll
        for (int e = 0; e < 4; ++e) {
            o8[e]     = f2bf(vx[2 * cc][e]);
            o8[4 + e] = f2bf(vx[2 * cc + 1][e]);
        }
        *(bf16x8*)(xnrow + 8 * cc) = o8;
    }
}

// ================= k_fat: fused QKV projection + attention per (i,h) =================
__global__ __launch_bounds__(512, 4)   // <=128 VGPR; LDS 37.4KB; 2 blocks/CU
void k_fat(char* __restrict__ ws)
{
    __shared__ short kls[256][40];   // 20,480 B  k[tok][d]   (stride 80B: 16B-aligned, 2-way banks)
    __shared__ short vls[32][264];   // 16,896 B  vT[d][tok]  (stride 528B: 2-way banks)

    const int tid  = threadIdx.x;
    const int lane = tid & 63;
    const int wid  = tid >> 6;
    const int g    = lane >> 4;
    const int l16  = lane & 15;
    const int ih   = blockIdx.x;          // grid 1024
    const int i    = ih >> 2;
    const int h    = ih & 3;

    const short* xn   = (const short*)(ws + XN_OFF) + (size_t)i * NJ * NC;
    const short* wqkv = (const short*)(ws + WB_OFF);
    const float* tbm  = (const float*)(ws + TBM_OFF) + (size_t)ih * NJ;
    short* og = (short*)(ws + OG_OFF) + ((size_t)h * (NI * NJ) + (size_t)i * NJ) * ND;

    const f32x4 z4 = {0.f, 0.f, 0.f, 0.f};
    bf16x8 qf[2];

    // ---- Phase A: wave projects q,k,v for its own 32 tokens ----
    #pragma unroll
    for (int tile = 0; tile < 2; ++tile) {
        const int tq = wid * 32 + tile * 16;
        bf16x8 af[4];
        #pragma unroll
        for (int ks = 0; ks < 4; ++ks)
            af[ks] = *(const bf16x8*)(xn + (size_t)(tq + l16) * NC + ks * 32 + g * 8);

        // q computed SWAPPED: D[dim][tok] (tok on lanes) -> xchg -> B-fragment
        {
            f32x4 ae = z4, ao = z4;
            #pragma unroll
            for (int ks = 0; ks < 4; ++ks) {
                bf16x8 w0 = *(const bf16x8*)(wqkv + (size_t)(h * 32 + l16) * NC + ks * 32 + g * 8);
                bf16x8 w1 = *(const bf16x8*)(wqkv + (size_t)(h * 32 + 16 + l16) * NC + ks * 32 + g * 8);
                ae = __builtin_amdgcn_mfma_f32_16x16x32_bf16(w0, af[ks], ae, 0, 0, 0);
                ao = __builtin_amdgcn_mfma_f32_16x16x32_bf16(w1, af[ks], ao, 0, 0, 0);
            }
            qf[tile] = xchg(ae, ao, g, l16);
        }
        // k: D[tok][dim] -> kls[tok][dim]
        #pragma unroll
        for (int sub = 0; sub < 2; ++sub) {
            f32x4 acc = z4;
            #pragma unroll
            for (int ks = 0; ks < 4; ++ks) {
                bf16x8 w = *(const bf16x8*)(wqkv + (size_t)(128 + h * 32 + sub * 16 + l16) * NC + ks * 32 + g * 8);
                acc = __builtin_amdgcn_mfma_f32_16x16x32_bf16(af[ks], w, acc, 0, 0, 0);
            }
            #pragma unroll
            for (int r = 0; r < 4; ++r)
                kls[tq + g * 4 + r][sub * 16 + l16] = f2bf(acc[r]);
        }
        // v: D[tok][dim] -> vls[dim][tok] (8B chunks)
        #pragma unroll
        for (int sub = 0; sub < 2; ++sub) {
            f32x4 acc = z4;
            #pragma unroll
            for (int ks = 0; ks < 4; ++ks) {
                bf16x8 w = *(const bf16x8*)(wqkv + (size_t)(256 + h * 32 + sub * 16 + l16) * NC + ks * 32 + g * 8);
                acc = __builtin_amdgcn_mfma_f32_16x16x32_bf16(af[ks], w, acc, 0, 0, 0);
            }
            bf16x4 pk;
            #pragma unroll
            for (int r = 0; r < 4; ++r) pk[r] = f2bf(acc[r]);
            *(bf16x4*)(&vls[sub * 16 + l16][tq + g * 4]) = pk;
        }
    }
    __syncthreads();   // the only barrier

    const float SCALE = 0.17677669529663687f;  // 1/sqrt(32)

    // ---- Phase B: swapped attention; lane owns q = tq + l16 ----
    #pragma unroll
    for (int qt = 0; qt < 2; ++qt) {
        const int tq = wid * 32 + qt * 16;
        const float tbq = tbm[tq + l16];

        f32x4 s[16];
        #pragma unroll
        for (int kt = 0; kt < 16; ++kt) {
            bf16x8 kf = *(const bf16x8*)(&kls[kt * 16 + l16][g * 8]);
            s[kt] = __builtin_amdgcn_mfma_f32_16x16x32_bf16(kf, qf[qt], z4, 0, 0, 0);
        }
        // fp32 scale + per-query bias (masked rows collapse to -1e9 exactly)
        #pragma unroll
        for (int kt = 0; kt < 16; ++kt)
            #pragma unroll
            for (int r = 0; r < 4; ++r)
                s[kt][r] = fmaf(s[kt][r], SCALE, tbq);

        // row max: 63 in-lane + 2 cross-group shfl
        float m = s[0][0];
        #pragma unroll
        for (int kt = 0; kt < 16; ++kt)
            #pragma unroll
            for (int r = 0; r < 4; ++r) m = fmaxf(m, s[kt][r]);
        m = fmaxf(m, __shfl_xor(m, 16));
        m = fmaxf(m, __shfl_xor(m, 32));

        float sum = 0.f;
        #pragma unroll
        for (int kt = 0; kt < 16; ++kt)
            #pragma unroll
            for (int r = 0; r < 4; ++r) { s[kt][r] = __expf(s[kt][r] - m); sum += s[kt][r]; }
        sum += __shfl_xor(sum, 16);
        sum += __shfl_xor(sum, 32);
        const float inv = 1.0f / sum;
        #pragma unroll
        for (int kt = 0; kt < 16; ++kt)
            #pragma unroll
            for (int r = 0; r < 4; ++r) s[kt][r] *= inv;

        // PV: P-fragment built in-register via xchg (no LDS round-trip)
        f32x4 o0 = z4, o1 = z4;
        #pragma unroll
        for (int c = 0; c < 8; ++c) {
            bf16x8 pa  = xchg(s[2 * c], s[2 * c + 1], g, l16);
            bf16x8 vb0 = *(const bf16x8*)(&vls[l16][c * 32 + g * 8]);
            bf16x8 vb1 = *(const bf16x8*)(&vls[16 + l16][c * 32 + g * 8]);
            o0 = __builtin_amdgcn_mfma_f32_16x16x32_bf16(pa, vb0, o0, 0, 0, 0);
            o1 = __builtin_amdgcn_mfma_f32_16x16x32_bf16(pa, vb1, o1, 0, 0, 0);
        }

        // O store: og[tok][d], two 32B segments per row
        #pragma unroll
        for (int r = 0; r < 4; ++r) {
            const int tok = tq + g * 4 + r;
            og[(size_t)tok * ND + l16]      = f2bf(o0[r]);
            og[(size_t)tok * ND + 16 + l16] = f2bf(o1[r]);
        }
    }
}

// ================= k_oproj: out = O @ wo^T + bias  (no LDS, no barrier) =================
__global__ __launch_bounds__(256, 4)
void k_oproj(const char* __restrict__ ws, const float* __restrict__ wo_b,
             float* __restrict__ out)
{
    const int tid  = threadIdx.x;
    const int lane = tid & 63;
    const int wid  = tid >> 6;        // 4 waves, wave owns 32 output cols
    const int g    = lane >> 4;
    const int l16  = lane & 15;
    const size_t tok0 = (size_t)blockIdx.x * 64;   // grid 1024

    const short* ogb = (const short*)(ws + OG_OFF);
    const short* wob = (const short*)(ws + WO_BF_OFF);
    const f32x4 z4 = {0.f, 0.f, 0.f, 0.f};

    bf16x8 bfr[2][4];
    #pragma unroll
    for (int s = 0; s < 2; ++s)
        #pragma unroll
        for (int ks = 0; ks < 4; ++ks)
            bfr[s][ks] = *(const bf16x8*)(wob + (size_t)(wid * 32 + s * 16 + l16) * NC + ks * 32 + g * 8);

    const float bias0 = wo_b[wid * 32 + l16];
    const float bias1 = wo_b[wid * 32 + 16 + l16];

    #pragma unroll
    for (int mt = 0; mt < 4; ++mt) {
        bf16x8 av[4];
        #pragma unroll
        for (int ks = 0; ks < 4; ++ks)
            av[ks] = *(const bf16x8*)(ogb + ((size_t)ks * (NI * NJ) + tok0 + mt * 16 + l16) * ND + g * 8);
        f32x4 a0 = z4, a1 = z4;
        #pragma unroll
        for (int ks = 0; ks < 4; ++ks) {
            a0 = __builtin_amdgcn_mfma_f32_16x16x32_bf16(av[ks], bfr[0][ks], a0, 0, 0, 0);
            a1 = __builtin_amdgcn_mfma_f32_16x16x32_bf16(av[ks], bfr[1][ks], a1, 0, 0, 0);
        }
        #pragma unroll
        for (int r = 0; r < 4; ++r) {
            const size_t row = (tok0 + mt * 16 + g * 4 + r) * NC;
            out[row + wid * 32 + l16]      = a0[r] + bias0;
            out[row + wid * 32 + 16 + l16] = a1[r] + bias1;
        }
    }
}

extern "C" void kernel_launch(void* const* d_in, const int* in_sizes, int n_in,
                              void* d_out, int out_size, void* d_ws, size_t ws_size,
                              hipStream_t stream) {
    const float* x    = (const float*)d_in[0];
    const float* mask = (const float*)d_in[1];
    const float* ln_g = (const float*)d_in[2];
    const float* ln_b = (const float*)d_in[3];
    const float* wq   = (const float*)d_in[4];
    const float* wk   = (const float*)d_in[5];
    const float* wv   = (const float*)d_in[6];
    const float* wb   = (const float*)d_in[7];
    const float* wo   = (const float*)d_in[8];
    const float* wo_b = (const float*)d_in[9];
    float* out = (float*)d_out;
    char* ws   = (char*)d_ws;

    k_pre  <<<dim3(1056),   dim3(256), 0, stream>>>(x, mask, ln_g, ln_b, wb, wq, wk, wv, wo, ws);
    k_fat  <<<dim3(NI * NH), dim3(512), 0, stream>>>(ws);
    k_oproj<<<dim3(1024),   dim3(256), 0, stream>>>(ws, wo_b, out);
}

// Round 6
// 114.893 us; speedup vs baseline: 1.0538x; 1.0538x over previous
//
#include <hip/hip_runtime.h>
#include <hip/hip_bf16.h>

typedef short bf16x8 __attribute__((ext_vector_type(8)));
typedef short bf16x4 __attribute__((ext_vector_type(4)));
typedef float f32x4  __attribute__((ext_vector_type(4)));

#define NI 256
#define NJ 256
#define NC 128
#define NH 4
#define ND 32

// ---- workspace layout (bytes) ----
#define WB_OFF    0           // wqkv bf16 [384][128] (row = op*128 + h*32 + d)
#define WO_BF_OFF 98304       // wo bf16 [128][128]
#define GB_OFF    131072      // f32: G[4] = sum g*wb_h, B[4] = sum b*wb_h
#define XN_OFF    131584      // xn bf16 [65536 tok][128]
#define TBM_OFF   16908800    // [1024 ih][256] f32 (tb + mask bias)
// end = 17,957,376 bytes

__device__ __forceinline__ short f2bf(float f) {
    return __builtin_bit_cast(short, __float2bfloat16(f));
}

// ================= k_prep: weight conversion + G/B constants =================
__global__ __launch_bounds__(256, 8)
void k_prep(const float* __restrict__ wq, const float* __restrict__ wk,
            const float* __restrict__ wv, const float* __restrict__ wo,
            const float* __restrict__ ln_g, const float* __restrict__ ln_b,
            const float* __restrict__ wb, char* __restrict__ ws)
{
    const int bid = blockIdx.x;
    const int tid = threadIdx.x;
    if (bid < 32) {   // 65536 f32 -> bf16, 8 per thread
        const int base = (bid * 256 + tid) * 8;
        const float* src;
        short* dst;
        if (base < 49152) {
            const int t = base >> 14;   // 0=q 1=k 2=v
            src = (t == 0 ? wq : (t == 1 ? wk : wv)) + (base & 16383);
            dst = (short*)(ws + WB_OFF) + base;
        } else {
            src = wo + (base - 49152);
            dst = (short*)(ws + WO_BF_OFF) + (base - 49152);
        }
        #pragma unroll
        for (int u = 0; u < 2; ++u) {
            f32x4 v = *(const f32x4*)(src + 4 * u);
            bf16x4 o;
            #pragma unroll
            for (int r = 0; r < 4; ++r) o[r] = f2bf(v[r]);
            *(bf16x4*)(dst + 4 * u) = o;
        }
    } else if (tid < 64) {   // bid==32: G[h], B[h]
        float G[4] = {0.f, 0.f, 0.f, 0.f}, Bv[4] = {0.f, 0.f, 0.f, 0.f};
        #pragma unroll
        for (int u = 0; u < 2; ++u) {
            const int c = tid * 2 + u;
            const float gc = ln_g[c], bc = ln_b[c];
            #pragma unroll
            for (int h = 0; h < 4; ++h) {
                const float w = wb[h * NC + c];
                G[h] += gc * w; Bv[h] += bc * w;
            }
        }
        #pragma unroll
        for (int dd = 1; dd < 64; dd <<= 1) {
            #pragma unroll
            for (int h = 0; h < 4; ++h) {
                G[h]  += __shfl_xor(G[h], dd);
                Bv[h] += __shfl_xor(Bv[h], dd);
            }
        }
        if (tid == 0) {
            float* GB = (float*)(ws + GB_OFF);
            #pragma unroll
            for (int h = 0; h < 4; ++h) { GB[h] = G[h]; GB[4 + h] = Bv[h]; }
        }
    }
}

// ================= k_pre: LayerNorm + tb + mask bias (lane-linear coalesced) =================
// Per load-instr k: lanes 0-31 hold token 2k, lanes 32-63 hold token 2k+1 (4 ch each).
__global__ __launch_bounds__(256, 8)
void k_pre(const float* __restrict__ x, const float* __restrict__ mask,
           const float* __restrict__ ln_g, const float* __restrict__ ln_b,
           char* __restrict__ ws)
{
    const int tid  = threadIdx.x;
    const int lane = tid & 63;
    const int wv   = tid >> 6;
    const int l5   = lane & 31;
    const int half = lane >> 5;
    const int c0   = l5 * 4;

    f32x4 gv = *(const f32x4*)(ln_g + c0);
    f32x4 bv = *(const f32x4*)(ln_b + c0);
    const float* GB = (const float*)(ws + GB_OFF);
    float Gh[4], Bh[4];
    f32x4 gwv[4];
    #pragma unroll
    for (int h = 0; h < 4; ++h) {
        Gh[h] = GB[h]; Bh[h] = GB[4 + h];
        f32x4 w = *(const f32x4*)((const float*)nullptr + 0);  // placeholder (replaced below)
        (void)w;
    }
    // gwv = g * wb  (per-lane 4 channels)  — wb accessed via ws? wb not needed: use original pointer
    // (we fold it below; wb rows are small & L2-hot)
    const float* wbp = nullptr; (void)wbp;
    // NOTE: wb is passed via ws-independent path: recompute gwv from global wb through GB? No —
    // we need per-channel wb. Load from the original wb pointer passed in x-kernel? We pass wb too.
    short* xnb = (short*)(ws + XN_OFF);
    float* tbm = (float*)(ws + TBM_OFF);

    // wb is the 6th parameter — declared below in real signature; this block replaced in actual code.
    const int t0 = blockIdx.x * 64 + wv * 16;
    (void)t0; (void)xnb; (void)tbm; (void)gv; (void)bv; (void)gwv; (void)half; (void)c0;
}

// real k_pre (with wb parameter)
__global__ __launch_bounds__(256, 8)
void k_pre2(const float* __restrict__ x, const float* __restrict__ mask,
            const float* __restrict__ ln_g, const float* __restrict__ ln_b,
            const float* __restrict__ wb, char* __restrict__ ws)
{
    const int tid  = threadIdx.x;
    const int lane = tid & 63;
    const int wv   = tid >> 6;
    const int l5   = lane & 31;
    const int half = lane >> 5;
    const int c0   = l5 * 4;

    f32x4 gv = *(const f32x4*)(ln_g + c0);
    f32x4 bv = *(const f32x4*)(ln_b + c0);
    f32x4 gwv[4];
    #pragma unroll
    for (int h = 0; h < 4; ++h) {
        f32x4 w = *(const f32x4*)(wb + h * NC + c0);
        #pragma unroll
        for (int e = 0; e < 4; ++e) gwv[h][e] = gv[e] * w[e];
    }
    const float* GB = (const float*)(ws + GB_OFF);
    float Gh[4], Bh[4];
    #pragma unroll
    for (int h = 0; h < 4; ++h) { Gh[h] = GB[h]; Bh[h] = GB[4 + h]; }

    short* xnb = (short*)(ws + XN_OFF);
    float* tbm = (float*)(ws + TBM_OFF);
    const int t0 = blockIdx.x * 64 + wv * 16;   // grid 1024, 4 waves, 16 tok/wave

    #pragma unroll
    for (int it = 0; it < 2; ++it) {
        const int tb8 = t0 + it * 8;
        const float* bp = x + (size_t)tb8 * NC;
        #pragma unroll
        for (int k = 0; k < 4; ++k) {
            f32x4 v = *(const f32x4*)(bp + k * 256 + lane * 4);   // lane-linear 16B
            const int tk = tb8 + k * 2 + half;
            float s  = v[0] + v[1] + v[2] + v[3];
            float s2 = v[0]*v[0] + v[1]*v[1] + v[2]*v[2] + v[3]*v[3];
            float d0 = v[0]*gwv[0][0] + v[1]*gwv[0][1] + v[2]*gwv[0][2] + v[3]*gwv[0][3];
            float d1 = v[0]*gwv[1][0] + v[1]*gwv[1][1] + v[2]*gwv[1][2] + v[3]*gwv[1][3];
            float d2 = v[0]*gwv[2][0] + v[1]*gwv[2][1] + v[2]*gwv[2][2] + v[3]*gwv[2][3];
            float d3 = v[0]*gwv[3][0] + v[1]*gwv[3][1] + v[2]*gwv[3][2] + v[3]*gwv[3][3];
            #pragma unroll
            for (int dd = 1; dd < 32; dd <<= 1) {
                s  += __shfl_xor(s, dd);
                s2 += __shfl_xor(s2, dd);
                d0 += __shfl_xor(d0, dd);
                d1 += __shfl_xor(d1, dd);
                d2 += __shfl_xor(d2, dd);
                d3 += __shfl_xor(d3, dd);
            }
            const float mu  = s * 0.0078125f;
            const float var = s2 * 0.0078125f - mu * mu;
            const float rs  = rsqrtf(var + 1e-5f);
            bf16x4 o;
            #pragma unroll
            for (int e = 0; e < 4; ++e) o[e] = f2bf((v[e] - mu) * rs * gv[e] + bv[e]);
            *(bf16x4*)(xnb + (size_t)tk * NC + c0) = o;
            if (l5 == 0) {
                const float mb = 1.0e9f * (mask[tk] - 1.0f);
                const int ii = tk >> 8, jj = tk & 255;
                const float d4[4] = {d0, d1, d2, d3};
                #pragma unroll
                for (int h = 0; h < 4; ++h)
                    tbm[(size_t)(ii * NH + h) * NJ + jj] = rs * (d4[h] - mu * Gh[h]) + Bh[h] + mb;
            }
        }
    }
}

// ================= k_fat2: per-i block — 4 heads of (proj + attn) + fused oproj =================
// 1024 threads = 16 waves; LDS 147,968 B -> 1 block/CU (= the 4-wave/SIMD VGPR regime's capacity).
#define SMEM_FAT 147968
__global__ __launch_bounds__(1024, 4)
void k_fat2(const char* __restrict__ ws, const float* __restrict__ wo_b,
            float* __restrict__ out)
{
    extern __shared__ __align__(16) char smem[];
    short (*kls)[40]  = (short(*)[40])(smem);             // [256][40]  20,480 B
    short (*vls)[264] = (short(*)[264])(smem + 20480);    // [32][264]  16,896 B
    // per-wave 2 slots of [16][40] (q staging + P double-buffer): 2560 B/wave
    // ols [256][136] at 78,336 (S/8=17 odd -> conflict-free b128 reads)
    short (*ols)[136] = (short(*)[136])(smem + 78336);    // 69,632 B  (total 147,968)

    const int tid  = threadIdx.x;
    const int lane = tid & 63;
    const int wid  = tid >> 6;          // 0..15
    const int g    = lane >> 4;
    const int l16  = lane & 15;
    const int i    = blockIdx.x;        // grid 256
    const int tq   = wid * 16;

    short* qsl = (short*)(smem + 37376) + wid * 1280;     // [2][16][40]

    const short* xn   = (const short*)(ws + XN_OFF) + (size_t)i * NJ * NC;
    const short* wqkv = (const short*)(ws + WB_OFF);
    const short* wob  = (const short*)(ws + WO_BF_OFF);
    const float* tbmB = (const float*)(ws + TBM_OFF) + (size_t)i * NH * NJ;

    const f32x4 z4 = {0.f, 0.f, 0.f, 0.f};
    const float SCALE = 0.17677669529663687f;  // 1/sqrt(32)

    for (int h = 0; h < NH; ++h) {
        // ---- Phase A: wave projects q,k,v for its 16 tokens ----
        bf16x8 af[4];
        #pragma unroll
        for (int ks = 0; ks < 4; ++ks)
            af[ks] = *(const bf16x8*)(xn + (size_t)(tq + l16) * NC + ks * 32 + g * 8);
        #pragma unroll
        for (int sub = 0; sub < 2; ++sub) {   // q -> qsl slot 0
            f32x4 acc = z4;
            #pragma unroll
            for (int ks = 0; ks < 4; ++ks) {
                bf16x8 w = *(const bf16x8*)(wqkv + (size_t)(h * 32 + sub * 16 + l16) * NC + ks * 32 + g * 8);
                acc = __builtin_amdgcn_mfma_f32_16x16x32_bf16(af[ks], w, acc, 0, 0, 0);
            }
            #pragma unroll
            for (int r = 0; r < 4; ++r)
                qsl[(g * 4 + r) * 40 + sub * 16 + l16] = f2bf(acc[r]);
        }
        #pragma unroll
        for (int sub = 0; sub < 2; ++sub) {   // k -> kls
            f32x4 acc = z4;
            #pragma unroll
            for (int ks = 0; ks < 4; ++ks) {
                bf16x8 w = *(const bf16x8*)(wqkv + (size_t)(128 + h * 32 + sub * 16 + l16) * NC + ks * 32 + g * 8);
                acc = __builtin_amdgcn_mfma_f32_16x16x32_bf16(af[ks], w, acc, 0, 0, 0);
            }
            #pragma unroll
            for (int r = 0; r < 4; ++r)
                kls[tq + g * 4 + r][sub * 16 + l16] = f2bf(acc[r]);
        }
        #pragma unroll
        for (int sub = 0; sub < 2; ++sub) {   // v -> vls (transposed)
            f32x4 acc = z4;
            #pragma unroll
            for (int ks = 0; ks < 4; ++ks) {
                bf16x8 w = *(const bf16x8*)(wqkv + (size_t)(256 + h * 32 + sub * 16 + l16) * NC + ks * 32 + g * 8);
                acc = __builtin_amdgcn_mfma_f32_16x16x32_bf16(af[ks], w, acc, 0, 0, 0);
            }
            bf16x4 pk;
            #pragma unroll
            for (int r = 0; r < 4; ++r) pk[r] = f2bf(acc[r]);
            *(bf16x4*)(&vls[sub * 16 + l16][tq + g * 4]) = pk;
        }
        __syncthreads();

        // ---- Phase B: attention for the wave's 16 queries ----
        const float* tbm = tbmB + (size_t)h * NJ;
        f32x4 tbmb = *(const f32x4*)(tbm + tq + g * 4);
        bf16x8 qf = *(const bf16x8*)(qsl + l16 * 40 + g * 8);

        f32x4 s[16];
        #pragma unroll
        for (int kt = 0; kt < 16; ++kt) {
            bf16x8 kf = *(const bf16x8*)(&kls[kt * 16 + l16][g * 8]);
            s[kt] = __builtin_amdgcn_mfma_f32_16x16x32_bf16(qf, kf, z4, 0, 0, 0);
        }
        #pragma unroll
        for (int kt = 0; kt < 16; ++kt)
            #pragma unroll
            for (int r = 0; r < 4; ++r)
                s[kt][r] = fmaf(s[kt][r], SCALE, tbmb[r]);  // fp32: masked rows collapse exactly

        f32x4 mx = s[0];
        #pragma unroll
        for (int kt = 1; kt < 16; ++kt)
            #pragma unroll
            for (int r = 0; r < 4; ++r) mx[r] = fmaxf(mx[r], s[kt][r]);
        #pragma unroll
        for (int d = 1; d < 16; d <<= 1)
            #pragma unroll
            for (int r = 0; r < 4; ++r) mx[r] = fmaxf(mx[r], __shfl_xor(mx[r], d));

        f32x4 sum = z4;
        #pragma unroll
        for (int kt = 0; kt < 16; ++kt)
            #pragma unroll
            for (int r = 0; r < 4; ++r) { s[kt][r] = __expf(s[kt][r] - mx[r]); sum[r] += s[kt][r]; }
        #pragma unroll
        for (int d = 1; d < 16; d <<= 1)
            #pragma unroll
            for (int r = 0; r < 4; ++r) sum[r] += __shfl_xor(sum[r], d);
        f32x4 inv;
        #pragma unroll
        for (int r = 0; r < 4; ++r) inv[r] = 1.0f / sum[r];
        #pragma unroll
        for (int kt = 0; kt < 16; ++kt)
            #pragma unroll
            for (int r = 0; r < 4; ++r) s[kt][r] *= inv[r];

        // PV: per-wave LDS staging (double-buffered slots), 32-key chunks
        f32x4 o0 = z4, o1 = z4;
        #pragma unroll
        for (int c = 0; c < 8; ++c) {
            short* pb = qsl + (c & 1) * 640;
            #pragma unroll
            for (int kk = 0; kk < 2; ++kk) {
                #pragma unroll
                for (int r = 0; r < 4; ++r)
                    pb[(g * 4 + r) * 40 + kk * 16 + l16] = f2bf(s[c * 2 + kk][r]);
            }
            bf16x8 a   = *(const bf16x8*)(pb + l16 * 40 + g * 8);
            bf16x8 vb0 = *(const bf16x8*)(&vls[l16][c * 32 + g * 8]);
            bf16x8 vb1 = *(const bf16x8*)(&vls[16 + l16][c * 32 + g * 8]);
            o0 = __builtin_amdgcn_mfma_f32_16x16x32_bf16(a, vb0, o0, 0, 0, 0);
            o1 = __builtin_amdgcn_mfma_f32_16x16x32_bf16(a, vb1, o1, 0, 0, 0);
        }

        // O slice -> ols (own rows only)
        #pragma unroll
        for (int r = 0; r < 4; ++r) {
            ols[tq + g * 4 + r][h * 32 + l16]      = f2bf(o0[r]);
            ols[tq + g * 4 + r][h * 32 + 16 + l16] = f2bf(o1[r]);
        }
        __syncthreads();   // protect kls/vls for next head
    }

    // ---- fused out-projection (same-wave rows of ols; no barrier needed) ----
    bf16x8 oaf[4];
    #pragma unroll
    for (int ks = 0; ks < 4; ++ks)
        oaf[ks] = *(const bf16x8*)(&ols[tq + l16][ks * 32 + g * 8]);
    #pragma unroll
    for (int ct = 0; ct < 8; ++ct) {
        bf16x8 bfr[4];
        #pragma unroll
        for (int ks = 0; ks < 4; ++ks)
            bfr[ks] = *(const bf16x8*)(wob + (size_t)(ct * 16 + l16) * NC + ks * 32 + g * 8);
        f32x4 acc = z4;
        #pragma unroll
        for (int ks = 0; ks < 4; ++ks)
            acc = __builtin_amdgcn_mfma_f32_16x16x32_bf16(oaf[ks], bfr[ks], acc, 0, 0, 0);
        const float bias = wo_b[ct * 16 + l16];
        #pragma unroll
        for (int r = 0; r < 4; ++r)
            out[((size_t)i * NJ + tq + g * 4 + r) * NC + ct * 16 + l16] = acc[r] + bias;
    }
}

extern "C" void kernel_launch(void* const* d_in, const int* in_sizes, int n_in,
                              void* d_out, int out_size, void* d_ws, size_t ws_size,
                              hipStream_t stream) {
    const float* x    = (const float*)d_in[0];
    const float* mask = (const float*)d_in[1];
    const float* ln_g = (const float*)d_in[2];
    const float* ln_b = (const float*)d_in[3];
    const float* wq   = (const float*)d_in[4];
    const float* wk   = (const float*)d_in[5];
    const float* wv   = (const float*)d_in[6];
    const float* wb   = (const float*)d_in[7];
    const float* wo   = (const float*)d_in[8];
    const float* wo_b = (const float*)d_in[9];
    float* out = (float*)d_out;
    char* ws   = (char*)d_ws;

    (void)hipFuncSetAttribute((const void*)k_fat2,
                              hipFuncAttributeMaxDynamicSharedMemorySize, SMEM_FAT);

    k_prep<<<dim3(33),   dim3(256), 0, stream>>>(wq, wk, wv, wo, ln_g, ln_b, wb, ws);
    k_pre2<<<dim3(1024), dim3(256), 0, stream>>>(x, mask, ln_g, ln_b, wb, ws);
    k_fat2<<<dim3(256),  dim3(1024), SMEM_FAT, stream>>>(ws, wo_b, out);
}